// Round 6
// baseline (960.794 us; speedup 1.0000x reference)
//
#include <hip/hip_runtime.h>
#include <math.h>

#define T_TRI 20000
#define KNN_K 20
#define H     128

// ---------------- workspace layout (bytes) ----------------
#define WS_GEO   0
#define WS_BQ    (1u<<20)
#define WS_NBR   (2u<<20)
#define WS_RS    (4u<<20)
#define WS_X     (5u<<20)
#define WS_Y     (16u<<20)
#define WS_S     (27u<<20)

__device__ __forceinline__ float readlane_f(float v, int l) {
    return __uint_as_float(__builtin_amdgcn_readlane(__float_as_uint(v), l));
}

// ---------------- geometry ----------------
__global__ void geom_kernel(const float* __restrict__ pts, const int* __restrict__ tris,
                            float* __restrict__ geo, float4* __restrict__ bq) {
    int t = blockIdx.x * blockDim.x + threadIdx.x;
    if (t >= T_TRI) return;
    int i0 = tris[3*t], i1 = tris[3*t+1], i2 = tris[3*t+2];
    float ax = pts[3*i0], ay = pts[3*i0+1], az = pts[3*i0+2];
    float bx = pts[3*i1], by = pts[3*i1+1], bz = pts[3*i1+2];
    float cx = pts[3*i2], cy = pts[3*i2+1], cz = pts[3*i2+2];
    float e0x = ax-bx, e0y = ay-by, e0z = az-bz;   // e_ij
    float e1x = ax-cx, e1y = ay-cy, e1z = az-cz;   // e_ik
    float e2x = bx-cx, e2y = by-cy, e2z = bz-cz;   // e_jk
    float mnx = fminf(fminf(e0x,e1x),e2x), mny = fminf(fminf(e0y,e1y),e2y), mnz = fminf(fminf(e0z,e1z),e2z);
    float mxx = fmaxf(fmaxf(e0x,e1x),e2x), mxy = fmaxf(fmaxf(e0y,e1y),e2y), mxz = fmaxf(fmaxf(e0z,e1z),e2z);
    float gx = (ax+bx+cx)*(1.0f/3.0f), gy = (ay+by+cy)*(1.0f/3.0f), gz = (az+bz+cz)*(1.0f/3.0f);
    float sq = (gx*gx + gy*gy) + gz*gz;
    float* g = geo + (size_t)t*12;
    g[0]=mnx; g[1]=mny; g[2]=mnz; g[3]=mxx; g[4]=mxy; g[5]=mxz;
    g[6]=gx;  g[7]=gy;  g[8]=gz;  g[9]=0.f; g[10]=0.f; g[11]=0.f;
    bq[t] = make_float4(gx, gy, gz, sq);
}

// ---------------- knn: 4 rows/wave, sorted top-21, readlane broadcasts ----------------
// One wave handles 4 rows; each candidate float4 read from LDS once feeds 4
// distance checks. Top-21 per row lives sorted ascending by (d,idx) across
// lanes 0..20. Wave-uniform (theta,maxidx) = lane 20's entry, fetched via
// v_readlane (SGPR, ~2cyc) instead of ds_bpermute. Candidate index for a
// drained event is recomputed scalar (kbase+src) — no shfl needed.
// DISTANCE ARITHMETIC IS THE R1/R3/R4-PROVEN ORDER (round-5 lesson: any
// reassociation flips near-tie selections vs the numpy reference):
//   dot = fmaf(qz,cz, fmaf(qy,cy, qx*cx)); d = (qw + c.w) - 2*dot.
// Pass check is d <= theta only: superset of the lex condition; stale/tie
// passes are rejected by the strict re-check inside the drain.
// Last tile padded with +INF candidates -> d = NaN or +INF, never passes.
#define KTILE 2048
__global__ __launch_bounds__(512) void knn_kernel(const float4* __restrict__ bq, int* __restrict__ nbr) {
    __shared__ float4 tile[KTILE];
    int wave = threadIdx.x >> 6;
    int lane = threadIdx.x & 63;
    int row0 = blockIdx.x * 32 + wave * 4;

    float4 q0 = bq[row0+0], q1 = bq[row0+1], q2 = bq[row0+2], q3 = bq[row0+3];

    float rd0 = INFINITY, rd1 = INFINITY, rd2 = INFINITY, rd3 = INFINITY;
    int   ri0 = 0x7FF00000 | lane, ri1 = ri0, ri2 = ri0, ri3 = ri0;  // distinct sentinels
    float th0 = INFINITY, th1 = INFINITY, th2 = INFINITY, th3 = INFINITY;
    int   mi0 = 0x7FFFFFFF, mi1 = 0x7FFFFFFF, mi2 = 0x7FFFFFFF, mi3 = 0x7FFFFFFF;

#define PROC_ROW(R)                                                                  \
    {                                                                                \
        float dot = fmaf(q##R.z, c.z, fmaf(q##R.y, c.y, q##R.x*c.x));                \
        float d = (q##R.w + c.w) - 2.0f*dot;                                         \
        unsigned long long bal = __ballot(d <= th##R);                               \
        while (bal) {                                                                \
            int src = __ffsll(bal) - 1;                                              \
            bal &= bal - 1;                                                          \
            float dc = readlane_f(d, src);                                           \
            int   jc = kbase + src;                                                  \
            if ((dc < th##R) || (dc == th##R && jc < mi##R)) {                       \
                bool less = (rd##R < dc) || (rd##R == dc && ri##R < jc);             \
                int pos = __popcll(__ballot(less) & 0x1FFFFFull);                    \
                float sd = __shfl_up(rd##R, 1);                                      \
                int   si = __shfl_up(ri##R, 1);                                      \
                if (lane < 21) {                                                     \
                    if (lane == pos)      { rd##R = dc; ri##R = jc; }                \
                    else if (lane > pos)  { rd##R = sd; ri##R = si; }                \
                }                                                                    \
                th##R = readlane_f(rd##R, 20);                                       \
                mi##R = __builtin_amdgcn_readlane(ri##R, 20);                        \
            }                                                                        \
        }                                                                            \
    }

    for (int base = 0; base < T_TRI; base += KTILE) {
        int n = min(KTILE, T_TRI - base);
        __syncthreads();
        for (int k = threadIdx.x; k < n; k += 512) tile[k] = bq[base + k];
        for (int k = n + threadIdx.x; k < KTILE; k += 512)
            tile[k] = make_float4(INFINITY, INFINITY, INFINITY, INFINITY);
        __syncthreads();
#pragma unroll 1
        for (int it = 0; it < KTILE/64; ++it) {
            int kbase = base + it*64;
            float4 c = tile[it*64 + lane];
            PROC_ROW(0)
            PROC_ROW(1)
            PROC_ROW(2)
            PROC_ROW(3)
        }
    }
#undef PROC_ROW
    // lane l holds rank-l entry; rank 0 = self, dropped (== reference idx[:,1:])
    if (lane >= 1 && lane < 21) {
        nbr[(row0+0)*KNN_K + lane - 1] = ri0;
        nbr[(row0+1)*KNN_K + lane - 1] = ri1;
        nbr[(row0+2)*KNN_K + lane - 1] = ri2;
        nbr[(row0+3)*KNN_K + lane - 1] = ri3;
    }
}

// ---------------- layer-0 helpers: y0[t][f] = p[t] * rowsum(W1b)[f] ----------------
__global__ void rowsum_kernel(const float* __restrict__ W1, float* __restrict__ rs) {
    int f = threadIdx.x;
    float s = 0.f;
    for (int c = 0; c < H; ++c) s += W1[f*137 + 9 + c];
    rs[f] = s;
}
__global__ void y0_kernel(const float* __restrict__ p, const float* __restrict__ rs, float* __restrict__ Y) {
    int tid = blockIdx.x * blockDim.x + threadIdx.x;   // over T*H
    int t = tid >> 7, f = tid & 127;
    Y[tid] = p[t] * rs[f];
}

// ---------------- edge accumulation: S[t] = sum_e relu(y[t]-y[tgt] + W1a*r9 + b1) ----------------
__global__ __launch_bounds__(128) void edge_kernel(const float* __restrict__ Y, const float* __restrict__ geo,
                            const int* __restrict__ nbr, const float* __restrict__ W1,
                            const float* __restrict__ b1, float* __restrict__ S) {
    __shared__ float W1aT[9][128];
    int f = threadIdx.x;
    for (int idx = threadIdx.x; idx < 9*128; idx += 128) {
        int ff = idx / 9, c = idx % 9;
        W1aT[c][ff] = W1[ff*137 + c];
    }
    __syncthreads();
    int t = blockIdx.x;
    const float4* g4 = (const float4*)geo;
    float4 s0 = g4[t*3+0], s1 = g4[t*3+1], s2 = g4[t*3+2];
    float b1f = b1[f];
    float ysrc = Y[(size_t)t*H + f];
    float acc = 0.f;
    for (int e = 0; e < KNN_K; ++e) {
        int tg = nbr[t*KNN_K + e];
        float4 t0 = g4[tg*3+0], t1 = g4[tg*3+1], t2 = g4[tg*3+2];
        float r0 = s0.x-t0.x, r1 = s0.y-t0.y, r2 = s0.z-t0.z, r3 = s0.w-t0.w;
        float r4 = s1.x-t1.x, r5 = s1.y-t1.y, r6 = s1.z-t1.z, r7 = s1.w-t1.w;
        float r8 = s2.x-t2.x;
        float g = b1f;
        g = fmaf(W1aT[0][f], r0, g); g = fmaf(W1aT[1][f], r1, g); g = fmaf(W1aT[2][f], r2, g);
        g = fmaf(W1aT[3][f], r3, g); g = fmaf(W1aT[4][f], r4, g);
        g = fmaf(W1aT[5][f], r5, g); g = fmaf(W1aT[6][f], r6, g);
        g = fmaf(W1aT[7][f], r7, g); g = fmaf(W1aT[8][f], r8, g);
        float pre = g + ysrc - Y[(size_t)tg*H + f];
        acc += fmaxf(pre, 0.f);
    }
    S[(size_t)t*H + f] = acc;
}

// ---------------- dense: C[t][f] = sum_c A[t][c]*W[f][wcol0+c] + bias[f]*bscale ----------------
// c4 outer / 8-row accumulators inner: 4 WT b32 reads held in registers are
// reused across 8 rows -> LDS issue per c4 drops from (8 bcast + 32 b32) to
// (4 b32 + 8 bcast). Per-row accumulation order stays c=0..127 (numerics
// identical to the R4-passing version). All acc indices compile-time (rule #20).
#define DTPB 32
__global__ __launch_bounds__(128) void dense_kernel(const float* __restrict__ A, const float* __restrict__ W,
                             int wstride, int wcol0, const float* __restrict__ bias, float bscale,
                             float* __restrict__ C) {
    __shared__ float WT[128][129];   // WT[c][f] = W[f][wcol0+c]
    __shared__ float Ar[8][128];
    int f = threadIdx.x;
    for (int r = 0; r < 128; ++r) WT[f][r] = W[r*wstride + wcol0 + f];  // thread f loads W[r][f] -> WT[f][r]
    float base = bias ? bias[f]*bscale : 0.0f;
    int t0 = blockIdx.x * DTPB;
    for (int tt = 0; tt < DTPB; tt += 8) {
        __syncthreads();
        for (int k = threadIdx.x; k < 8*128; k += 128) {
            int j = k >> 7;
            Ar[j][f] = A[(size_t)(t0+tt+j)*H + f];
        }
        __syncthreads();
        float a0 = base, a1 = base, a2 = base, a3 = base;
        float a4_ = base, a5 = base, a6 = base, a7 = base;
#pragma unroll
        for (int c4 = 0; c4 < 32; ++c4) {
            float w0 = WT[4*c4+0][f], w1 = WT[4*c4+1][f], w2 = WT[4*c4+2][f], w3 = WT[4*c4+3][f];
#define DROW(J, ACC)                                                        \
            {                                                               \
                float4 v = ((const float4*)Ar[J])[c4];                      \
                ACC = fmaf(w0, v.x, ACC); ACC = fmaf(w1, v.y, ACC);         \
                ACC = fmaf(w2, v.z, ACC); ACC = fmaf(w3, v.w, ACC);         \
            }
            DROW(0, a0) DROW(1, a1) DROW(2, a2) DROW(3, a3)
            DROW(4, a4_) DROW(5, a5) DROW(6, a6) DROW(7, a7)
#undef DROW
        }
        C[(size_t)(t0+tt+0)*H + f] = a0;
        C[(size_t)(t0+tt+1)*H + f] = a1;
        C[(size_t)(t0+tt+2)*H + f] = a2;
        C[(size_t)(t0+tt+3)*H + f] = a3;
        C[(size_t)(t0+tt+4)*H + f] = a4_;
        C[(size_t)(t0+tt+5)*H + f] = a5;
        C[(size_t)(t0+tt+6)*H + f] = a6;
        C[(size_t)(t0+tt+7)*H + f] = a7;
    }
}

// ---------------- final head ----------------
__global__ void final_kernel(const float* __restrict__ X, const float* __restrict__ Wf,
                             const float* __restrict__ bf, float* __restrict__ out) {
    int t = blockIdx.x, lane = threadIdx.x;   // 64 threads
    float a = X[(size_t)t*H + lane]*Wf[lane] + X[(size_t)t*H + 64 + lane]*Wf[64+lane];
#pragma unroll
    for (int off = 32; off >= 1; off >>= 1) a += __shfl_xor(a, off);
    if (lane == 0) {
        float z = a + bf[0];
        out[t] = 1.0f / (1.0f + expf(-z));
    }
}

extern "C" void kernel_launch(void* const* d_in, const int* in_sizes, int n_in,
                              void* d_out, int out_size, void* d_ws, size_t ws_size,
                              hipStream_t stream) {
    (void)in_sizes; (void)n_in; (void)out_size; (void)ws_size;
    const float* pts   = (const float*)d_in[0];
    const int*   tris  = (const int*)d_in[1];
    const float* probs = (const float*)d_in[2];
    const float* W1[3] = {(const float*)d_in[3],  (const float*)d_in[7],  (const float*)d_in[11]};
    const float* b1[3] = {(const float*)d_in[4],  (const float*)d_in[8],  (const float*)d_in[12]};
    const float* W2[3] = {(const float*)d_in[5],  (const float*)d_in[9],  (const float*)d_in[13]};
    const float* b2[3] = {(const float*)d_in[6],  (const float*)d_in[10], (const float*)d_in[14]};
    const float* Wf = (const float*)d_in[15];
    const float* bf = (const float*)d_in[16];
    float* out = (float*)d_out;

    char* ws = (char*)d_ws;
    float*  geo = (float*)(ws + WS_GEO);
    float4* bq  = (float4*)(ws + WS_BQ);
    int*    nbr = (int*)(ws + WS_NBR);
    float*  rs  = (float*)(ws + WS_RS);
    float*  X   = (float*)(ws + WS_X);
    float*  Y   = (float*)(ws + WS_Y);
    float*  S   = (float*)(ws + WS_S);

    geom_kernel<<<(T_TRI+255)/256, 256, 0, stream>>>(pts, tris, geo, bq);
    knn_kernel<<<T_TRI/32, 512, 0, stream>>>(bq, nbr);
    rowsum_kernel<<<1, 128, 0, stream>>>(W1[0], rs);
    y0_kernel<<<(T_TRI*H)/256, 256, 0, stream>>>(probs, rs, Y);
    for (int l = 0; l < 3; ++l) {
        if (l > 0)
            dense_kernel<<<T_TRI/DTPB, 128, 0, stream>>>(X, W1[l], 137, 9, nullptr, 0.f, Y);
        edge_kernel<<<T_TRI, 128, 0, stream>>>(Y, geo, nbr, W1[l], b1[l], S);
        dense_kernel<<<T_TRI/DTPB, 128, 0, stream>>>(S, W2[l], 128, 0, b2[l], (float)KNN_K, X);
    }
    final_kernel<<<T_TRI, 64, 0, stream>>>(X, Wf, bf, out);
}

// Round 7
// 563.849 us; speedup vs baseline: 1.7040x; 1.7040x over previous
//
#include <hip/hip_runtime.h>
#include <math.h>

#define T_TRI 20000
#define KNN_K 20
#define H     128

// ---------------- workspace layout (bytes) ----------------
#define WS_GEO   0
#define WS_BQ    (1u<<20)
#define WS_NBR   (2u<<20)
#define WS_RS    (4u<<20)          // rs: 512B
#define WS_WT    ((4u<<20)+4096)   // 5 transposed weights, 5*64KB = 320KB
#define WS_X     (5u<<20)
#define WS_Y     (16u<<20)
#define WS_S     (27u<<20)

__device__ __forceinline__ float readlane_f(float v, int l) {
    return __uint_as_float(__builtin_amdgcn_readlane(__float_as_uint(v), l));
}

// ---------------- geometry ----------------
__global__ void geom_kernel(const float* __restrict__ pts, const int* __restrict__ tris,
                            float* __restrict__ geo, float4* __restrict__ bq) {
    int t = blockIdx.x * blockDim.x + threadIdx.x;
    if (t >= T_TRI) return;
    int i0 = tris[3*t], i1 = tris[3*t+1], i2 = tris[3*t+2];
    float ax = pts[3*i0], ay = pts[3*i0+1], az = pts[3*i0+2];
    float bx = pts[3*i1], by = pts[3*i1+1], bz = pts[3*i1+2];
    float cx = pts[3*i2], cy = pts[3*i2+1], cz = pts[3*i2+2];
    float e0x = ax-bx, e0y = ay-by, e0z = az-bz;   // e_ij
    float e1x = ax-cx, e1y = ay-cy, e1z = az-cz;   // e_ik
    float e2x = bx-cx, e2y = by-cy, e2z = bz-cz;   // e_jk
    float mnx = fminf(fminf(e0x,e1x),e2x), mny = fminf(fminf(e0y,e1y),e2y), mnz = fminf(fminf(e0z,e1z),e2z);
    float mxx = fmaxf(fmaxf(e0x,e1x),e2x), mxy = fmaxf(fmaxf(e0y,e1y),e2y), mxz = fmaxf(fmaxf(e0z,e1z),e2z);
    float gx = (ax+bx+cx)*(1.0f/3.0f), gy = (ay+by+cy)*(1.0f/3.0f), gz = (az+bz+cz)*(1.0f/3.0f);
    float sq = (gx*gx + gy*gy) + gz*gz;
    float* g = geo + (size_t)t*12;
    g[0]=mnx; g[1]=mny; g[2]=mnz; g[3]=mxx; g[4]=mxy; g[5]=mxz;
    g[6]=gx;  g[7]=gy;  g[8]=gz;  g[9]=0.f; g[10]=0.f; g[11]=0.f;
    bq[t] = make_float4(gx, gy, gz, sq);
}

// ---------------- knn: 4 waves/block, 4 rows/wave, sorted top-21 ----------------
// 256-thread blocks (grid 1250, LDS 16KB) fix the R6 occupancy quantization
// (625 8-wave blocks -> 2.44 blocks/CU -> 44% occ). Candidate iteration order,
// distance arithmetic (R1/R3/R4-proven order: dot=fmaf(z,fmaf(y,x*x)); d=(qw+cw)-2dot),
// and event-drain order are IDENTICAL to the passing R6 kernel — the selected
// set is order-independent (strict lex total order on (d,idx)).
#define KTILE 1024
__global__ __launch_bounds__(256) void knn_kernel(const float4* __restrict__ bq, int* __restrict__ nbr) {
    __shared__ float4 tile[KTILE];
    int wave = threadIdx.x >> 6;
    int lane = threadIdx.x & 63;
    int row0 = blockIdx.x * 16 + wave * 4;

    float4 q0 = bq[row0+0], q1 = bq[row0+1], q2 = bq[row0+2], q3 = bq[row0+3];

    float rd0 = INFINITY, rd1 = INFINITY, rd2 = INFINITY, rd3 = INFINITY;
    int   ri0 = 0x7FF00000 | lane, ri1 = ri0, ri2 = ri0, ri3 = ri0;  // distinct sentinels
    float th0 = INFINITY, th1 = INFINITY, th2 = INFINITY, th3 = INFINITY;
    int   mi0 = 0x7FFFFFFF, mi1 = 0x7FFFFFFF, mi2 = 0x7FFFFFFF, mi3 = 0x7FFFFFFF;

#define PROC_ROW(R)                                                                  \
    {                                                                                \
        float dot = fmaf(q##R.z, c.z, fmaf(q##R.y, c.y, q##R.x*c.x));                \
        float d = (q##R.w + c.w) - 2.0f*dot;                                         \
        unsigned long long bal = __ballot(d <= th##R);                               \
        while (bal) {                                                                \
            int src = __ffsll(bal) - 1;                                              \
            bal &= bal - 1;                                                          \
            float dc = readlane_f(d, src);                                           \
            int   jc = kbase + src;                                                  \
            if ((dc < th##R) || (dc == th##R && jc < mi##R)) {                       \
                bool less = (rd##R < dc) || (rd##R == dc && ri##R < jc);             \
                int pos = __popcll(__ballot(less) & 0x1FFFFFull);                    \
                float sd = __shfl_up(rd##R, 1);                                      \
                int   si = __shfl_up(ri##R, 1);                                      \
                if (lane < 21) {                                                     \
                    if (lane == pos)      { rd##R = dc; ri##R = jc; }                \
                    else if (lane > pos)  { rd##R = sd; ri##R = si; }                \
                }                                                                    \
                th##R = readlane_f(rd##R, 20);                                       \
                mi##R = __builtin_amdgcn_readlane(ri##R, 20);                        \
            }                                                                        \
        }                                                                            \
    }

    for (int base = 0; base < T_TRI; base += KTILE) {
        int n = min(KTILE, T_TRI - base);
        __syncthreads();
        for (int k = threadIdx.x; k < n; k += 256) tile[k] = bq[base + k];
        for (int k = n + threadIdx.x; k < KTILE; k += 256)
            tile[k] = make_float4(INFINITY, INFINITY, INFINITY, INFINITY);
        __syncthreads();
#pragma unroll 1
        for (int it = 0; it < KTILE/64; ++it) {
            int kbase = base + it*64;
            float4 c = tile[it*64 + lane];
            PROC_ROW(0)
            PROC_ROW(1)
            PROC_ROW(2)
            PROC_ROW(3)
        }
    }
#undef PROC_ROW
    // lane l holds rank-l entry; rank 0 = self, dropped (== reference idx[:,1:])
    if (lane >= 1 && lane < 21) {
        nbr[(row0+0)*KNN_K + lane - 1] = ri0;
        nbr[(row0+1)*KNN_K + lane - 1] = ri1;
        nbr[(row0+2)*KNN_K + lane - 1] = ri2;
        nbr[(row0+3)*KNN_K + lane - 1] = ri3;
    }
}

// ---------------- layer-0 helpers: y0[t][f] = p[t] * rowsum(W1b)[f] ----------------
__global__ void rowsum_kernel(const float* __restrict__ W1, float* __restrict__ rs) {
    int f = threadIdx.x;
    float s = 0.f;
    for (int c = 0; c < H; ++c) s += W1[f*137 + 9 + c];
    rs[f] = s;
}
__global__ void y0_kernel(const float* __restrict__ p, const float* __restrict__ rs, float* __restrict__ Y) {
    int tid = blockIdx.x * blockDim.x + threadIdx.x;   // over T*H
    int t = tid >> 7, f = tid & 127;
    Y[tid] = p[t] * rs[f];
}

// ---------------- weight pre-transpose (once, tiny) ----------------
// WTg[m][c4][f][k] = W_m[f][col0 + 4*c4 + k]  (m*16384 + c4*512 + f*4 + k)
// Interleaved so dense's inner loop reads one coalesced float4 per thread.
__global__ void wtrans_kernel(const float* __restrict__ W11, const float* __restrict__ W12,
                              const float* __restrict__ W20, const float* __restrict__ W21,
                              const float* __restrict__ W22, float* __restrict__ WTg) {
    int f = threadIdx.x, c = blockIdx.x, m = blockIdx.y;
    const float* W; int stride, col0;
    if      (m == 0) { W = W11; stride = 137; col0 = 9; }
    else if (m == 1) { W = W12; stride = 137; col0 = 9; }
    else if (m == 2) { W = W20; stride = 128; col0 = 0; }
    else if (m == 3) { W = W21; stride = 128; col0 = 0; }
    else             { W = W22; stride = 128; col0 = 0; }
    WTg[m*16384 + (c>>2)*512 + f*4 + (c&3)] = W[f*stride + col0 + c];
}

// ---------------- dense: C[t][f] = sum_c A[t][c]*WT[c][f] + bias[f]*bscale ----------------
// No weight LDS (R6's 66KB WT capped occupancy at 2 blocks/CU). Weights come
// from the pre-transposed interleaved WTg: 1 coalesced dwordx4 per c4 (L2-hot,
// re-read per block: 1250*64KB = 80MB from L2 ~ 2.5us). LDS = 4KB (Ar only).
// Per-row accumulation order stays c=0..127 ascending — numerics identical.
#define DTPB 16
__global__ __launch_bounds__(128) void dense_kernel(const float* __restrict__ A, const float* __restrict__ WTg,
                             const float* __restrict__ bias, float bscale,
                             float* __restrict__ C) {
    __shared__ float Ar[8][128];
    int f = threadIdx.x;
    float base = bias ? bias[f]*bscale : 0.0f;
    int t0 = blockIdx.x * DTPB;
    for (int tt = 0; tt < DTPB; tt += 8) {
        __syncthreads();
#pragma unroll
        for (int j = 0; j < 8; ++j) Ar[j][f] = A[(size_t)(t0+tt+j)*H + f];
        __syncthreads();
        float a0 = base, a1 = base, a2 = base, a3 = base;
        float a4_ = base, a5 = base, a6 = base, a7 = base;
#pragma unroll
        for (int c4 = 0; c4 < 32; ++c4) {
            float4 w = *(const float4*)&WTg[c4*512 + f*4];
#define DROW(J, ACC)                                                        \
            {                                                               \
                float4 v = ((const float4*)Ar[J])[c4];                      \
                ACC = fmaf(w.x, v.x, ACC); ACC = fmaf(w.y, v.y, ACC);       \
                ACC = fmaf(w.z, v.z, ACC); ACC = fmaf(w.w, v.w, ACC);       \
            }
            DROW(0, a0) DROW(1, a1) DROW(2, a2) DROW(3, a3)
            DROW(4, a4_) DROW(5, a5) DROW(6, a6) DROW(7, a7)
#undef DROW
        }
        C[(size_t)(t0+tt+0)*H + f] = a0;
        C[(size_t)(t0+tt+1)*H + f] = a1;
        C[(size_t)(t0+tt+2)*H + f] = a2;
        C[(size_t)(t0+tt+3)*H + f] = a3;
        C[(size_t)(t0+tt+4)*H + f] = a4_;
        C[(size_t)(t0+tt+5)*H + f] = a5;
        C[(size_t)(t0+tt+6)*H + f] = a6;
        C[(size_t)(t0+tt+7)*H + f] = a7;
    }
}

// ---------------- edge accumulation: S[t] = sum_e relu(y[t]-y[tgt] + W1a*r9 + b1) ----------------
// Wave-per-triangle (4 triangles per 256-thread block): lane owns f=lane and
// f=lane+64; its 18 W1a coefficients are hoisted to registers after one LDS
// stage — the e-loop touches no LDS. Per-f math and accumulation order are
// identical to the R4/R6-passing version.
__global__ __launch_bounds__(256) void edge_kernel(const float* __restrict__ Y, const float* __restrict__ geo,
                            const int* __restrict__ nbr, const float* __restrict__ W1,
                            const float* __restrict__ b1, float* __restrict__ S) {
    __shared__ float W1aT[9][128];
    for (int idx = threadIdx.x; idx < 9*128; idx += 256) {
        int c = idx >> 7, ff = idx & 127;
        W1aT[c][ff] = W1[ff*137 + c];
    }
    __syncthreads();
    int wave = threadIdx.x >> 6, lane = threadIdx.x & 63;
    int t = blockIdx.x * 4 + wave;
    float wlo[9], whi[9];
#pragma unroll
    for (int c = 0; c < 9; ++c) { wlo[c] = W1aT[c][lane]; whi[c] = W1aT[c][64+lane]; }
    const float4* g4 = (const float4*)geo;
    float4 s0 = g4[t*3+0], s1 = g4[t*3+1], s2 = g4[t*3+2];
    float b1lo = b1[lane],            b1hi = b1[64+lane];
    float ylo  = Y[(size_t)t*H+lane], yhi  = Y[(size_t)t*H+64+lane];
    float accLo = 0.f, accHi = 0.f;
#pragma unroll
    for (int e = 0; e < KNN_K; ++e) {
        int tg = nbr[t*KNN_K + e];
        float4 t0 = g4[tg*3+0], t1 = g4[tg*3+1], t2 = g4[tg*3+2];
        float r0 = s0.x-t0.x, r1 = s0.y-t0.y, r2 = s0.z-t0.z, r3 = s0.w-t0.w;
        float r4 = s1.x-t1.x, r5 = s1.y-t1.y, r6 = s1.z-t1.z, r7 = s1.w-t1.w;
        float r8 = s2.x-t2.x;
        float gLo = b1lo;
        gLo = fmaf(wlo[0], r0, gLo); gLo = fmaf(wlo[1], r1, gLo); gLo = fmaf(wlo[2], r2, gLo);
        gLo = fmaf(wlo[3], r3, gLo); gLo = fmaf(wlo[4], r4, gLo);
        gLo = fmaf(wlo[5], r5, gLo); gLo = fmaf(wlo[6], r6, gLo);
        gLo = fmaf(wlo[7], r7, gLo); gLo = fmaf(wlo[8], r8, gLo);
        float gHi = b1hi;
        gHi = fmaf(whi[0], r0, gHi); gHi = fmaf(whi[1], r1, gHi); gHi = fmaf(whi[2], r2, gHi);
        gHi = fmaf(whi[3], r3, gHi); gHi = fmaf(whi[4], r4, gHi);
        gHi = fmaf(whi[5], r5, gHi); gHi = fmaf(whi[6], r6, gHi);
        gHi = fmaf(whi[7], r7, gHi); gHi = fmaf(whi[8], r8, gHi);
        float preLo = gLo + ylo - Y[(size_t)tg*H + lane];
        float preHi = gHi + yhi - Y[(size_t)tg*H + 64 + lane];
        accLo += fmaxf(preLo, 0.f);
        accHi += fmaxf(preHi, 0.f);
    }
    S[(size_t)t*H + lane]      = accLo;
    S[(size_t)t*H + 64 + lane] = accHi;
}

// ---------------- final head ----------------
__global__ void final_kernel(const float* __restrict__ X, const float* __restrict__ Wf,
                             const float* __restrict__ bf, float* __restrict__ out) {
    int t = blockIdx.x, lane = threadIdx.x;   // 64 threads
    float a = X[(size_t)t*H + lane]*Wf[lane] + X[(size_t)t*H + 64 + lane]*Wf[64+lane];
#pragma unroll
    for (int off = 32; off >= 1; off >>= 1) a += __shfl_xor(a, off);
    if (lane == 0) {
        float z = a + bf[0];
        out[t] = 1.0f / (1.0f + expf(-z));
    }
}

extern "C" void kernel_launch(void* const* d_in, const int* in_sizes, int n_in,
                              void* d_out, int out_size, void* d_ws, size_t ws_size,
                              hipStream_t stream) {
    (void)in_sizes; (void)n_in; (void)out_size; (void)ws_size;
    const float* pts   = (const float*)d_in[0];
    const int*   tris  = (const int*)d_in[1];
    const float* probs = (const float*)d_in[2];
    const float* W1[3] = {(const float*)d_in[3],  (const float*)d_in[7],  (const float*)d_in[11]};
    const float* b1[3] = {(const float*)d_in[4],  (const float*)d_in[8],  (const float*)d_in[12]};
    const float* W2[3] = {(const float*)d_in[5],  (const float*)d_in[9],  (const float*)d_in[13]};
    const float* b2[3] = {(const float*)d_in[6],  (const float*)d_in[10], (const float*)d_in[14]};
    const float* Wf = (const float*)d_in[15];
    const float* bf = (const float*)d_in[16];
    float* out = (float*)d_out;

    char* ws = (char*)d_ws;
    float*  geo = (float*)(ws + WS_GEO);
    float4* bq  = (float4*)(ws + WS_BQ);
    int*    nbr = (int*)(ws + WS_NBR);
    float*  rs  = (float*)(ws + WS_RS);
    float*  WTg = (float*)(ws + WS_WT);
    float*  X   = (float*)(ws + WS_X);
    float*  Y   = (float*)(ws + WS_Y);
    float*  S   = (float*)(ws + WS_S);

    geom_kernel<<<(T_TRI+255)/256, 256, 0, stream>>>(pts, tris, geo, bq);
    knn_kernel<<<T_TRI/16, 256, 0, stream>>>(bq, nbr);
    rowsum_kernel<<<1, 128, 0, stream>>>(W1[0], rs);
    wtrans_kernel<<<dim3(128,5), 128, 0, stream>>>(W1[1], W1[2], W2[0], W2[1], W2[2], WTg);
    y0_kernel<<<(T_TRI*H)/256, 256, 0, stream>>>(probs, rs, Y);
    for (int l = 0; l < 3; ++l) {
        if (l > 0)
            dense_kernel<<<T_TRI/DTPB, 128, 0, stream>>>(X, WTg + (size_t)(l-1)*16384, nullptr, 0.f, Y);
        edge_kernel<<<T_TRI/4, 256, 0, stream>>>(Y, geo, nbr, W1[l], b1[l], S);
        dense_kernel<<<T_TRI/DTPB, 128, 0, stream>>>(S, WTg + (size_t)(2+l)*16384, b2[l], (float)KNN_K, X);
    }
    final_kernel<<<T_TRI, 64, 0, stream>>>(X, Wf, bf, out);
}